// Round 12
// baseline (417.187 us; speedup 1.0000x reference)
//
#include <hip/hip_runtime.h>
#include <math.h>

#define NN 20000
#define EE 320000
#define ETOT 340000   // EE + NN self-loops
#define NHEADS 8
#define HID 64
#define HCV 512       // NHEADS*HID
#define IND 128
#define OUTD 128
#define NEG_SLOPE 0.2f
#define LOG2E 1.4426950408889634f

typedef __attribute__((ext_vector_type(8))) _Float16 half8;
typedef __attribute__((ext_vector_type(4))) _Float16 half4;
typedef __attribute__((ext_vector_type(4))) float floatx4;

#define S1 (IND * HCV)
#define S2 (HCV * HCV)
#define S3 (HCV * OUTD)
#define XTOT (NN * IND)

// ---------------- prep: LDS-tiled W transposes + vectorized x cvt + zero cnt ----------------
#define NT1 64
#define NT2 320      // 64 + 256
#define NT_TOT 384
#define XB 2500      // XTOT/1024
__global__ __launch_bounds__(256) void prep_kernel(const float* __restrict__ W1,
                                                   const float* __restrict__ W2,
                                                   const float* __restrict__ W3,
                                                   const float* __restrict__ x,
                                                   _Float16* __restrict__ T1,
                                                   _Float16* __restrict__ T2,
                                                   _Float16* __restrict__ T3,
                                                   _Float16* __restrict__ xh,
                                                   int* __restrict__ cnt) {
    int b = blockIdx.x;
    int tid = threadIdx.x;
    if (b < NT_TOT) {
        __shared__ _Float16 tile[32][34];
        const float* W; _Float16* T; int K, N, tb;
        if (b < NT1)      { W = W1; T = T1; K = IND; N = HCV;  tb = b; }
        else if (b < NT2) { W = W2; T = T2; K = HCV; N = HCV;  tb = b - NT1; }
        else              { W = W3; T = T3; K = HCV; N = OUTD; tb = b - NT2; }
        int ntn = N >> 5;
        int k0 = (tb / ntn) * 32, n0 = (tb % ntn) * 32;
        int tx = tid & 31, ty0 = tid >> 5;
        #pragma unroll
        for (int i = 0; i < 4; i++) {
            int ty = ty0 + 8 * i;
            tile[ty][tx] = (_Float16)W[(size_t)(k0 + ty) * N + n0 + tx];
        }
        __syncthreads();
        #pragma unroll
        for (int i = 0; i < 4; i++) {
            int ty = ty0 + 8 * i;
            T[(size_t)(n0 + ty) * K + k0 + tx] = tile[tx][ty];
        }
    } else if (b < NT_TOT + XB) {
        int idx = (b - NT_TOT) * 256 + tid;          // float4 index
        int j = idx * 4;
        float4 v = *(const float4*)&x[j];
        half4 o;
        o[0] = (_Float16)v.x; o[1] = (_Float16)v.y;
        o[2] = (_Float16)v.z; o[3] = (_Float16)v.w;
        *(half4*)&xh[j] = o;
    } else {
        int idx = (b - NT_TOT - XB) * 256 + tid;
        if (idx < NN) cnt[idx] = 0;
    }
}

// ---------------- CSR build ----------------

__global__ void count_kernel(const int* __restrict__ ei, int* __restrict__ cnt) {
    int i = blockIdx.x * blockDim.x + threadIdx.x;
    if (i >= ETOT) return;
    int v = (i < EE) ? ei[EE + i] : (i - EE);
    atomicAdd(&cnt[v], 1);
}

#define SCH 20
__global__ __launch_bounds__(1024) void scan_kernel(const int* __restrict__ cnt,
                                                    int* __restrict__ row_ptr,
                                                    int* __restrict__ cursor,
                                                    int* __restrict__ hist) {
    __shared__ int wtot[16];
    __shared__ int woff[16];
    int t = threadIdx.x;
    if (t < 256) hist[t] = 0;            // zero degree-histogram for the sort
    int lane = t & 63;
    int wid = t >> 6;
    int base = t * SCH;
    int vals[SCH];
    int s = 0;
    #pragma unroll
    for (int i = 0; i < SCH; i++) {
        int idx = base + i;
        int v = (idx < NN) ? cnt[idx] : 0;
        vals[i] = v;
        s += v;
    }
    int incl = s;
    #pragma unroll
    for (int off = 1; off < 64; off <<= 1) {
        int u = __shfl_up(incl, off);
        if (lane >= off) incl += u;
    }
    int excl = incl - s;
    if (lane == 63) wtot[wid] = incl;
    __syncthreads();
    if (t == 0) {
        int run = 0;
        #pragma unroll
        for (int j = 0; j < 16; j++) { woff[j] = run; run += wtot[j]; }
        row_ptr[NN] = run;
    }
    __syncthreads();
    int run = woff[wid] + excl;
    #pragma unroll
    for (int i = 0; i < SCH; i++) {
        int idx = base + i;
        if (idx < NN) { row_ptr[idx] = run; cursor[idx] = run; run += vals[i]; }
    }
}

__global__ void fill_kernel(const int* __restrict__ ei, int* __restrict__ cursor,
                            int* __restrict__ csr_src) {
    int i = blockIdx.x * blockDim.x + threadIdx.x;
    if (i >= ETOT) return;
    int u, v;
    if (i < EE) { u = ei[i]; v = ei[EE + i]; }
    else        { u = i - EE; v = i - EE; }
    int pos = atomicAdd(&cursor[v], 1);
    csr_src[pos] = u;
}

// ---------------- degree sort: histogram + 256-bin exclusive scan + scatter ----------------
__global__ void hist_kernel(const int* __restrict__ row_ptr, int* __restrict__ hist) {
    int v = blockIdx.x * blockDim.x + threadIdx.x;
    if (v >= NN) return;
    int deg = row_ptr[v + 1] - row_ptr[v];
    atomicAdd(&hist[min(deg, 255)], 1);
}

__global__ __launch_bounds__(256) void binscan_kernel(const int* __restrict__ hist,
                                                      int* __restrict__ binoff) {
    __shared__ int wt[4];
    int t = threadIdx.x;
    int lane = t & 63;
    int w = t >> 6;
    int v = hist[t];
    int incl = v;
    #pragma unroll
    for (int off = 1; off < 64; off <<= 1) {
        int u = __shfl_up(incl, off);
        if (lane >= off) incl += u;
    }
    if (lane == 63) wt[w] = incl;
    __syncthreads();
    int add = 0;
    for (int j = 0; j < w; j++) add += wt[j];
    binoff[t] = incl - v + add;          // exclusive prefix
}

__global__ void scatter_kernel(const int* __restrict__ row_ptr, int* __restrict__ binoff,
                               int* __restrict__ perm) {
    int v = blockIdx.x * blockDim.x + threadIdx.x;
    if (v >= NN) return;
    int deg = row_ptr[v + 1] - row_ptr[v];
    int pos = atomicAdd(&binoff[min(deg, 255)], 1);
    perm[pos] = v;
}

// ---------------- MFMA GEMM 128x128 (layers 1 & 2): double-buffered global_load_lds ----------------
// 2-phase pipeline: prologue-stage buf0; per K-step {stage next -> ds_read+MFMA cur ->
// __syncthreads -> flip}. LDS tiles linear [128][32] f16; 16B slot XOR-swizzled via per-lane
// GLOBAL source address (linear dest + inverse-swz source + swz read); ds_read addrs hoisted.
#define BK 32
#define TILE_E (128 * BK)        // elements per tile buffer
#define TILE_B (TILE_E * 2)      // bytes per tile buffer
__global__ __launch_bounds__(512) void gemm_al(const _Float16* __restrict__ A,
                                               const _Float16* __restrict__ Bt,
                                               _Float16* __restrict__ C16,
                                               const float* __restrict__ a_src,
                                               const float* __restrict__ a_dst,
                                               float* __restrict__ als2,
                                               float* __restrict__ ald2,
                                               int M, int K) {
    __shared__ _Float16 sA[2 * TILE_E];
    __shared__ _Float16 sB[2 * TILE_E];
    __shared__ float psum_s[4][128];
    __shared__ float psum_d[4][128];
    int tid = threadIdx.x;
    int lane = tid & 63;
    int wid = tid >> 6;          // 0..7
    int wv_m = wid >> 2;         // 0..1 : 64-row half
    int wv_n = wid & 3;          // 0..3 : 32-col slice
    int m0 = blockIdx.x * 128, n0 = blockIdx.y * 128;
    int quad = lane >> 4;
    int l15 = lane & 15;

    // staging: wave wid owns phys bytes [wid*1024, wid*1024+1024) of each tile
    int phys = wid * 1024 + lane * 16;
    int logical = phys ^ (((phys >> 7) & 3) << 4);   // same row, swizzled 16B slot
    int lrow = logical >> 6;                          // 0..127
    int lcol = (logical >> 4) & 3;                    // 16B slot in row
    int gmA = m0 + lrow;
    const _Float16* gA = A + (size_t)gmA * K + lcol * 8;
    const _Float16* gB = Bt + (size_t)(n0 + lrow) * K + lcol * 8;
    bool aok = (gmA < M);

    // hoisted swizzled ds_read byte offsets
    int ra[4], rb[2];
    #pragma unroll
    for (int i = 0; i < 4; i++) {
        int lb = (wv_m * 64 + i * 16 + l15) * 64 + quad * 16;
        ra[i] = lb ^ (((lb >> 7) & 3) << 4);
    }
    #pragma unroll
    for (int j = 0; j < 2; j++) {
        int lb = (wv_n * 32 + j * 16 + l15) * 64 + quad * 16;
        rb[j] = lb ^ (((lb >> 7) & 3) << 4);
    }

    floatx4 acc[4][2] = {};

    int nt = K / BK;
    int cur = 0;
    {
        _Float16* lA = sA + wid * 512;
        _Float16* lB = sB + wid * 512;
        if (aok)
            __builtin_amdgcn_global_load_lds(
                (const __attribute__((address_space(1))) void*)gA,
                (__attribute__((address_space(3))) void*)lA, 16, 0, 0);
        __builtin_amdgcn_global_load_lds(
            (const __attribute__((address_space(1))) void*)gB,
            (__attribute__((address_space(3))) void*)lB, 16, 0, 0);
    }
    __syncthreads();
    for (int t = 0; t < nt; ++t) {
        if (t + 1 < nt) {
            int k1 = (t + 1) * BK;
            _Float16* lA = sA + (cur ^ 1) * TILE_E + wid * 512;
            _Float16* lB = sB + (cur ^ 1) * TILE_E + wid * 512;
            if (aok)
                __builtin_amdgcn_global_load_lds(
                    (const __attribute__((address_space(1))) void*)(gA + k1),
                    (__attribute__((address_space(3))) void*)lA, 16, 0, 0);
            __builtin_amdgcn_global_load_lds(
                (const __attribute__((address_space(1))) void*)(gB + k1),
                (__attribute__((address_space(3))) void*)lB, 16, 0, 0);
        }
        const char* bA = (const char*)sA + cur * TILE_B;
        const char* bB = (const char*)sB + cur * TILE_B;
        half8 a[4], b[2];
        #pragma unroll
        for (int i = 0; i < 4; i++)
            a[i] = *(const half8*)(bA + ra[i]);
        #pragma unroll
        for (int j = 0; j < 2; j++)
            b[j] = *(const half8*)(bB + rb[j]);
        #pragma unroll
        for (int i = 0; i < 4; i++)
            #pragma unroll
            for (int j = 0; j < 2; j++)
                acc[i][j] = __builtin_amdgcn_mfma_f32_16x16x32_f16(a[i], b[j], acc[i][j], 0, 0, 0);
        __syncthreads();     // drains this step's stage (vmcnt) + ds_reads (lgkm)
        cur ^= 1;
    }
    #pragma unroll
    for (int i = 0; i < 4; i++) {
        #pragma unroll
        for (int r = 0; r < 4; r++) {
            int gm = m0 + wv_m * 64 + i * 16 + quad * 4 + r;
            if (gm < M) {
                #pragma unroll
                for (int j = 0; j < 2; j++)
                    C16[(size_t)gm * HCV + n0 + wv_n * 32 + j * 16 + l15] = (_Float16)acc[i][j][r];
            }
        }
    }
    // fused half-logit epilogue (prescaled by log2e); als/ald head-major [h][node]
    int h0 = n0 >> 6;
    int hh = h0 + (wv_n >> 1);
    float as_v[2], ad_v[2];
    #pragma unroll
    for (int j = 0; j < 2; j++) {
        int dim = (wv_n * 32 + j * 16 + l15) & 63;
        as_v[j] = a_src[hh * HID + dim] * LOG2E;
        ad_v[j] = a_dst[hh * HID + dim] * LOG2E;
    }
    #pragma unroll
    for (int i = 0; i < 4; i++) {
        #pragma unroll
        for (int r = 0; r < 4; r++) {
            float ps = acc[i][0][r] * as_v[0] + acc[i][1][r] * as_v[1];
            float pd = acc[i][0][r] * ad_v[0] + acc[i][1][r] * ad_v[1];
            #pragma unroll
            for (int off = 1; off <= 8; off <<= 1) {
                ps += __shfl_xor(ps, off);
                pd += __shfl_xor(pd, off);
            }
            if (l15 == 0) {
                int row = wv_m * 64 + i * 16 + quad * 4 + r;   // 0..127
                psum_s[wv_n][row] = ps;
                psum_d[wv_n][row] = pd;
            }
        }
    }
    __syncthreads();
    if (tid < 128) {
        int gm = m0 + tid;
        if (gm < M) {
            als2[(size_t)h0 * NN + gm]       = psum_s[0][tid] + psum_s[1][tid];
            als2[(size_t)(h0 + 1) * NN + gm] = psum_s[2][tid] + psum_s[3][tid];
            ald2[(size_t)h0 * NN + gm]       = psum_d[0][tid] + psum_d[1][tid];
            ald2[(size_t)(h0 + 1) * NN + gm] = psum_d[2][tid] + psum_d[3][tid];
        }
    }
}

// ---------------- MFMA GEMM 128x128 (layer 3): double-buffered, single-head al3 ----------------
__global__ __launch_bounds__(512) void gemm3(const _Float16* __restrict__ A,
                                             const _Float16* __restrict__ Bt,
                                             _Float16* __restrict__ C16,
                                             const float* __restrict__ a_src,
                                             const float* __restrict__ a_dst,
                                             float* __restrict__ als,
                                             float* __restrict__ ald,
                                             int M, int K) {
    __shared__ _Float16 sA[2 * TILE_E];
    __shared__ _Float16 sB[2 * TILE_E];
    __shared__ float psum_s[4][128];
    __shared__ float psum_d[4][128];
    int tid = threadIdx.x;
    int lane = tid & 63;
    int wid = tid >> 6;          // 0..7
    int wv_m = wid >> 2;         // 0..1
    int wv_n = wid & 3;          // 0..3
    int m0 = blockIdx.x * 128;
    int quad = lane >> 4;
    int l15 = lane & 15;

    int phys = wid * 1024 + lane * 16;
    int logical = phys ^ (((phys >> 7) & 3) << 4);
    int lrow = logical >> 6;
    int lcol = (logical >> 4) & 3;
    int gmA = m0 + lrow;
    const _Float16* gA = A + (size_t)gmA * K + lcol * 8;
    const _Float16* gB = Bt + (size_t)lrow * K + lcol * 8;   // n0 = 0, 128 rows = all of OUTD
    bool aok = (gmA < M);

    int ra[4], rb[2];
    #pragma unroll
    for (int i = 0; i < 4; i++) {
        int lb = (wv_m * 64 + i * 16 + l15) * 64 + quad * 16;
        ra[i] = lb ^ (((lb >> 7) & 3) << 4);
    }
    #pragma unroll
    for (int j = 0; j < 2; j++) {
        int lb = (wv_n * 32 + j * 16 + l15) * 64 + quad * 16;
        rb[j] = lb ^ (((lb >> 7) & 3) << 4);
    }

    floatx4 acc[4][2] = {};

    int nt = K / BK;
    int cur = 0;
    {
        _Float16* lA = sA + wid * 512;
        _Float16* lB = sB + wid * 512;
        if (aok)
            __builtin_amdgcn_global_load_lds(
                (const __attribute__((address_space(1))) void*)gA,
                (__attribute__((address_space(3))) void*)lA, 16, 0, 0);
        __builtin_amdgcn_global_load_lds(
            (const __attribute__((address_space(1))) void*)gB,
            (__attribute__((address_space(3))) void*)lB, 16, 0, 0);
    }
    __syncthreads();
    for (int t = 0; t < nt; ++t) {
        if (t + 1 < nt) {
            int k1 = (t + 1) * BK;
            _Float16* lA = sA + (cur ^ 1) * TILE_E + wid * 512;
            _Float16* lB = sB + (cur ^ 1) * TILE_E + wid * 512;
            if (aok)
                __builtin_amdgcn_global_load_lds(
                    (const __attribute__((address_space(1))) void*)(gA + k1),
                    (__attribute__((address_space(3))) void*)lA, 16, 0, 0);
            __builtin_amdgcn_global_load_lds(
                (const __attribute__((address_space(1))) void*)(gB + k1),
                (__attribute__((address_space(3))) void*)lB, 16, 0, 0);
        }
        const char* bA = (const char*)sA + cur * TILE_B;
        const char* bB = (const char*)sB + cur * TILE_B;
        half8 a[4], b[2];
        #pragma unroll
        for (int i = 0; i < 4; i++)
            a[i] = *(const half8*)(bA + ra[i]);
        #pragma unroll
        for (int j = 0; j < 2; j++)
            b[j] = *(const half8*)(bB + rb[j]);
        #pragma unroll
        for (int i = 0; i < 4; i++)
            #pragma unroll
            for (int j = 0; j < 2; j++)
                acc[i][j] = __builtin_amdgcn_mfma_f32_16x16x32_f16(a[i], b[j], acc[i][j], 0, 0, 0);
        __syncthreads();
        cur ^= 1;
    }
    #pragma unroll
    for (int i = 0; i < 4; i++) {
        #pragma unroll
        for (int r = 0; r < 4; r++) {
            int gm = m0 + wv_m * 64 + i * 16 + quad * 4 + r;
            if (gm < M) {
                #pragma unroll
                for (int j = 0; j < 2; j++)
                    C16[(size_t)gm * OUTD + wv_n * 32 + j * 16 + l15] = (_Float16)acc[i][j][r];
            }
        }
    }
    // single-head al3 epilogue (prescaled by log2e): reduce over all 128 cols
    float as_v[2], ad_v[2];
    #pragma unroll
    for (int j = 0; j < 2; j++) {
        int dim = wv_n * 32 + j * 16 + l15;      // 0..127
        as_v[j] = a_src[dim] * LOG2E;
        ad_v[j] = a_dst[dim] * LOG2E;
    }
    #pragma unroll
    for (int i = 0; i < 4; i++) {
        #pragma unroll
        for (int r = 0; r < 4; r++) {
            float ps = acc[i][0][r] * as_v[0] + acc[i][1][r] * as_v[1];
            float pd = acc[i][0][r] * ad_v[0] + acc[i][1][r] * ad_v[1];
            #pragma unroll
            for (int off = 1; off <= 8; off <<= 1) {
                ps += __shfl_xor(ps, off);
                pd += __shfl_xor(pd, off);
            }
            if (l15 == 0) {
                int row = wv_m * 64 + i * 16 + quad * 4 + r;   // 0..127
                psum_s[wv_n][row] = ps;
                psum_d[wv_n][row] = pd;
            }
        }
    }
    __syncthreads();
    if (tid < 128) {
        int gm = m0 + tid;
        if (gm < M) {
            als[gm] = psum_s[0][tid] + psum_s[1][tid] + psum_s[2][tid] + psum_s[3][tid];
            ald[gm] = psum_d[0][tid] + psum_d[1][tid] + psum_d[2][tid] + psum_d[3][tid];
        }
    }
}

// ---------------- gather (layers 1 & 2): degree-sorted, wave = (1 head, 4 nodes x 2 walkers) ----------------
// v = perm[idx]: counting-sorted by degree, so the 4 nodes in a wave have near-equal degree
// (wave time = max of group ranges -> ~mean). head = blockIdx.x & 7 keeps the per-XCD working
// set at one head slice (2.56 MB h + 80 KB als). shfl_xor(8) combines the 2 walkers.
__global__ __launch_bounds__(256) void gather_kernel(const _Float16* __restrict__ h,
                                                     const int* __restrict__ row_ptr,
                                                     const int* __restrict__ csr_src,
                                                     const int* __restrict__ perm,
                                                     const float* __restrict__ als2,
                                                     const float* __restrict__ ald2,
                                                     const float* __restrict__ bias,
                                                     _Float16* __restrict__ gout) {
    int tid = threadIdx.x;
    int lane = tid & 63;
    int wid = tid >> 6;
    int bid = blockIdx.x;
    int hd = bid & 7;                    // head == XCD (round-robin)
    int dl = lane & 7;                   // dim octet within the head
    int es = (lane >> 3) & 1;            // edge-walker slot
    int sub = lane >> 4;                 // node slot 0..3
    int vidx = (bid >> 3) * 16 + wid * 4 + sub;
    if (vidx >= NN) return;
    int v = perm[vidx];
    const float* asl = als2 + (size_t)hd * NN;
    float adst = ald2[(size_t)hd * NN + v];
    int s0 = row_ptr[v], s1 = row_ptr[v + 1];
    int mid = (s0 + s1 + 1) >> 1;
    int jb = es ? mid : s0;
    int je = es ? s1 : mid;
    const _Float16* hh = h + hd * HID + dl * 8;
    float acc[8] = {};
    float l = 0.f;
    int j = jb;
    for (; j + 4 <= je; j += 4) {
        int u[4]; float p[4]; half8 xv[4];
        #pragma unroll
        for (int e = 0; e < 4; e++) u[e] = csr_src[j + e];
        #pragma unroll
        for (int e = 0; e < 4; e++) xv[e] = *(const half8*)&hh[(size_t)u[e] * HCV];
        #pragma unroll
        for (int e = 0; e < 4; e++) {
            float t = asl[u[e]] + adst;
            t = fmaxf(t, NEG_SLOPE * t);             // leaky_relu, slope<1
            p[e] = exp2f(fminf(t, 115.f));
        }
        #pragma unroll
        for (int e = 0; e < 4; e++) {
            l += p[e];
            #pragma unroll
            for (int k = 0; k < 8; k++)
                acc[k] = fmaf(p[e], (float)xv[e][k], acc[k]);
        }
    }
    for (; j < je; j++) {
        int u0 = csr_src[j];
        half8 x0 = *(const half8*)&hh[(size_t)u0 * HCV];
        float t0 = asl[u0] + adst;
        t0 = fmaxf(t0, NEG_SLOPE * t0);
        float p0 = exp2f(fminf(t0, 115.f));
        l += p0;
        #pragma unroll
        for (int k = 0; k < 8; k++)
            acc[k] = fmaf(p0, (float)x0[k], acc[k]);
    }
    // combine the two walkers (lanes differ only in bit 3)
    l += __shfl_xor(l, 8);
    #pragma unroll
    for (int k = 0; k < 8; k++)
        acc[k] += __shfl_xor(acc[k], 8);
    if (es == 0) {
        float inv = 1.f / (l + 1e-16f);
        half8 hv;
        #pragma unroll
        for (int k = 0; k < 8; k++) {
            float o = fmaf(acc[k], inv, bias[hd * HID + dl * 8 + k]);
            o = (o > 0.f) ? o : (__expf(o) - 1.f);   // ELU
            hv[k] = (_Float16)o;
        }
        half8* dst = (half8*)&gout[(size_t)v * HCV + hd * HID + dl * 8];
        __builtin_nontemporal_store(hv, dst);
    }
}

// ---------------- layer-3 gather: degree-sorted, single-pass, wave = (1 dim-half, 4 nodes x 2 walkers) ----------------
__global__ __launch_bounds__(256) void gather3_kernel(const _Float16* __restrict__ h,
                                                      const int* __restrict__ row_ptr,
                                                      const int* __restrict__ csr_src,
                                                      const int* __restrict__ perm,
                                                      const float* __restrict__ als,
                                                      const float* __restrict__ ald,
                                                      const float* __restrict__ bias,
                                                      float* __restrict__ out) {
    int tid = threadIdx.x;
    int lane = tid & 63;
    int wid = tid >> 6;
    int bid = blockIdx.x;
    int dh = bid & 1;                    // dim-half (XCD parity)
    int dl = lane & 7;
    int es = (lane >> 3) & 1;
    int sub = lane >> 4;                 // node slot 0..3
    int vidx = (bid >> 1) * 16 + wid * 4 + sub;
    if (vidx >= NN) return;
    int v = perm[vidx];
    float adst = ald[v];
    int s0 = row_ptr[v], s1 = row_ptr[v + 1];
    int mid = (s0 + s1 + 1) >> 1;
    int jb = es ? mid : s0;
    int je = es ? s1 : mid;
    const _Float16* hh = h + dh * 64 + dl * 8;
    float acc[8] = {};
    float l = 0.f;
    int j = jb;
    for (; j + 4 <= je; j += 4) {
        int u[4]; float p[4]; half8 xv[4];
        #pragma unroll
        for (int e = 0; e < 4; e++) u[e] = csr_src[j + e];
        #pragma unroll
        for (int e = 0; e < 4; e++) xv[e] = *(const half8*)&hh[(size_t)u[e] * OUTD];
        #pragma unroll
        for (int e = 0; e < 4; e++) {
            float t = als[u[e]] + adst;
            t = fmaxf(t, NEG_SLOPE * t);
            p[e] = exp2f(fminf(t, 115.f));
        }
        #pragma unroll
        for (int e = 0; e < 4; e++) {
            l += p[e];
            #pragma unroll
            for (int k = 0; k < 8; k++)
                acc[k] = fmaf(p[e], (float)xv[e][k], acc[k]);
        }
    }
    for (; j < je; j++) {
        int u0 = csr_src[j];
        half8 x0 = *(const half8*)&hh[(size_t)u0 * OUTD];
        float t0 = als[u0] + adst;
        t0 = fmaxf(t0, NEG_SLOPE * t0);
        float p0 = exp2f(fminf(t0, 115.f));
        l += p0;
        #pragma unroll
        for (int k = 0; k < 8; k++)
            acc[k] = fmaf(p0, (float)x0[k], acc[k]);
    }
    l += __shfl_xor(l, 8);
    #pragma unroll
    for (int k = 0; k < 8; k++)
        acc[k] += __shfl_xor(acc[k], 8);
    if (es == 0) {
        float inv = 1.f / (l + 1e-16f);
        float4 o0, o1;
        o0.x = fmaf(acc[0], inv, bias[dh * 64 + dl * 8 + 0]);
        o0.y = fmaf(acc[1], inv, bias[dh * 64 + dl * 8 + 1]);
        o0.z = fmaf(acc[2], inv, bias[dh * 64 + dl * 8 + 2]);
        o0.w = fmaf(acc[3], inv, bias[dh * 64 + dl * 8 + 3]);
        o1.x = fmaf(acc[4], inv, bias[dh * 64 + dl * 8 + 4]);
        o1.y = fmaf(acc[5], inv, bias[dh * 64 + dl * 8 + 5]);
        o1.z = fmaf(acc[6], inv, bias[dh * 64 + dl * 8 + 6]);
        o1.w = fmaf(acc[7], inv, bias[dh * 64 + dl * 8 + 7]);
        size_t base = (size_t)v * OUTD + dh * 64 + dl * 8;
        *(float4*)&out[base] = o0;
        *(float4*)&out[base + 4] = o1;
    }
}

// ---------------- launch ----------------

extern "C" void kernel_launch(void* const* d_in, const int* in_sizes, int n_in,
                              void* d_out, int out_size, void* d_ws, size_t ws_size,
                              hipStream_t stream) {
    const float* x     = (const float*)d_in[0];
    const int*   ei    = (const int*)d_in[1];
    const float* W1    = (const float*)d_in[2];
    const float* as1   = (const float*)d_in[3];
    const float* ad1   = (const float*)d_in[4];
    const float* b1    = (const float*)d_in[5];
    const float* W2    = (const float*)d_in[6];
    const float* as2   = (const float*)d_in[7];
    const float* ad2   = (const float*)d_in[8];
    const float* b2    = (const float*)d_in[9];
    const float* W3    = (const float*)d_in[10];
    const float* as3   = (const float*)d_in[11];
    const float* ad3   = (const float*)d_in[12];
    const float* b3    = (const float*)d_in[13];
    float* out = (float*)d_out;

    size_t off = 0;
    auto carve = [&](size_t bytes) {
        void* p = (char*)d_ws + off;
        off += (bytes + 255) & ~(size_t)255;
        return p;
    };
    int* row_ptr   = (int*)carve((NN + 1) * sizeof(int));
    int* cursor    = (int*)carve(NN * sizeof(int));
    int* csr_src   = (int*)carve(ETOT * sizeof(int));
    int* perm      = (int*)carve(NN * sizeof(int));
    int* hist      = (int*)carve(256 * sizeof(int));
    int* binoff    = (int*)carve(256 * sizeof(int));
    _Float16* xh   = (_Float16*)carve((size_t)NN * IND * sizeof(_Float16));
    _Float16* h1   = (_Float16*)carve((size_t)NN * HCV * sizeof(_Float16));
    _Float16* gact = (_Float16*)carve((size_t)NN * HCV * sizeof(_Float16));
    _Float16* hf16 = (_Float16*)carve((size_t)NN * HCV * sizeof(_Float16));
    _Float16* h3   = (_Float16*)carve((size_t)NN * OUTD * sizeof(_Float16));
    float* als     = (float*)carve((size_t)NN * NHEADS * sizeof(float));
    float* ald     = (float*)carve((size_t)NN * NHEADS * sizeof(float));
    _Float16* W1T  = (_Float16*)carve((size_t)S1 * sizeof(_Float16));
    _Float16* W2T  = (_Float16*)carve((size_t)S2 * sizeof(_Float16));
    _Float16* W3T  = (_Float16*)carve((size_t)S3 * sizeof(_Float16));
    _Float16* gact2 = h1;   // aliases h1 (dead after layer-1 gather)
    (void)ws_size; (void)n_in; (void)in_sizes; (void)out_size;

    dim3 blk(256);

    // ---- prep (tiled transposes + x cvt + cnt zero) ----
    int prep_blocks = NT_TOT + XB + (NN + 255) / 256;
    prep_kernel<<<prep_blocks, blk, 0, stream>>>(W1, W2, W3, x, W1T, W2T, W3T, xh, cursor);

    // ---- CSR build + degree sort ----
    count_kernel<<<(ETOT + 255) / 256, blk, 0, stream>>>(ei, cursor);
    scan_kernel<<<1, 1024, 0, stream>>>(cursor, row_ptr, cursor, hist);
    fill_kernel<<<(ETOT + 255) / 256, blk, 0, stream>>>(ei, cursor, csr_src);
    hist_kernel<<<(NN + 255) / 256, blk, 0, stream>>>(row_ptr, hist);
    binscan_kernel<<<1, 256, 0, stream>>>(hist, binoff);
    scatter_kernel<<<(NN + 255) / 256, blk, 0, stream>>>(row_ptr, binoff, perm);

    int mt128 = (NN + 127) / 128;
    int nb4 = (NN + 15) / 16;   // node-blocks for gathers (4 waves x 4 nodes per block)

    // ---- layer 1: project-first (dense GEMM + fused al), then head-sliced gather ----
    gemm_al<<<dim3(mt128, HCV / 128), dim3(512), 0, stream>>>(xh, W1T, h1, as1, ad1, als, ald, NN, IND);
    gather_kernel<<<dim3(nb4 * 8), blk, 0, stream>>>(h1, row_ptr, csr_src, perm, als, ald, b1, gact);

    // ---- layer 2: identical structure ----
    gemm_al<<<dim3(mt128, HCV / 128), dim3(512), 0, stream>>>(gact, W2T, hf16, as2, ad2, als, ald, NN, HCV);
    gather_kernel<<<dim3(nb4 * 8), blk, 0, stream>>>(hf16, row_ptr, csr_src, perm, als, ald, b2, gact2);

    // ---- layer 3: output-side, fp16 h3, dim-half sliced single-pass gather ----
    gemm3<<<dim3(mt128, 1), dim3(512), 0, stream>>>(gact2, W3T, h3, as3, ad3, als, ald, NN, HCV);
    gather3_kernel<<<dim3(nb4 * 2), blk, 0, stream>>>(h3, row_ptr, csr_src, perm, als, ald, b3, out);
}

// Round 13
// 304.638 us; speedup vs baseline: 1.3694x; 1.3694x over previous
//
#include <hip/hip_runtime.h>
#include <math.h>

#define NN 20000
#define EE 320000
#define ETOT 340000   // EE + NN self-loops
#define NHEADS 8
#define HID 64
#define HCV 512       // NHEADS*HID
#define IND 128
#define OUTD 128
#define NEG_SLOPE 0.2f
#define LOG2E 1.4426950408889634f

typedef __attribute__((ext_vector_type(8))) _Float16 half8;
typedef __attribute__((ext_vector_type(4))) _Float16 half4;
typedef __attribute__((ext_vector_type(4))) float floatx4;

#define S1 (IND * HCV)
#define S2 (HCV * HCV)
#define S3 (HCV * OUTD)
#define XTOT (NN * IND)

// ---------------- prep: LDS-tiled W transposes + vectorized x cvt + zero cnt ----------------
#define NT1 64
#define NT2 320      // 64 + 256
#define NT_TOT 384
#define XB 2500      // XTOT/1024
__global__ __launch_bounds__(256) void prep_kernel(const float* __restrict__ W1,
                                                   const float* __restrict__ W2,
                                                   const float* __restrict__ W3,
                                                   const float* __restrict__ x,
                                                   _Float16* __restrict__ T1,
                                                   _Float16* __restrict__ T2,
                                                   _Float16* __restrict__ T3,
                                                   _Float16* __restrict__ xh,
                                                   int* __restrict__ cnt) {
    int b = blockIdx.x;
    int tid = threadIdx.x;
    if (b < NT_TOT) {
        __shared__ _Float16 tile[32][34];
        const float* W; _Float16* T; int K, N, tb;
        if (b < NT1)      { W = W1; T = T1; K = IND; N = HCV;  tb = b; }
        else if (b < NT2) { W = W2; T = T2; K = HCV; N = HCV;  tb = b - NT1; }
        else              { W = W3; T = T3; K = HCV; N = OUTD; tb = b - NT2; }
        int ntn = N >> 5;
        int k0 = (tb / ntn) * 32, n0 = (tb % ntn) * 32;
        int tx = tid & 31, ty0 = tid >> 5;
        #pragma unroll
        for (int i = 0; i < 4; i++) {
            int ty = ty0 + 8 * i;
            tile[ty][tx] = (_Float16)W[(size_t)(k0 + ty) * N + n0 + tx];
        }
        __syncthreads();
        #pragma unroll
        for (int i = 0; i < 4; i++) {
            int ty = ty0 + 8 * i;
            T[(size_t)(n0 + ty) * K + k0 + tx] = tile[tx][ty];
        }
    } else if (b < NT_TOT + XB) {
        int idx = (b - NT_TOT) * 256 + tid;          // float4 index
        int j = idx * 4;
        float4 v = *(const float4*)&x[j];
        half4 o;
        o[0] = (_Float16)v.x; o[1] = (_Float16)v.y;
        o[2] = (_Float16)v.z; o[3] = (_Float16)v.w;
        *(half4*)&xh[j] = o;
    } else {
        int idx = (b - NT_TOT - XB) * 256 + tid;
        if (idx < NN) cnt[idx] = 0;
    }
}

// ---------------- CSR build ----------------

__global__ void count_kernel(const int* __restrict__ ei, int* __restrict__ cnt) {
    int i = blockIdx.x * blockDim.x + threadIdx.x;
    if (i >= ETOT) return;
    int v = (i < EE) ? ei[EE + i] : (i - EE);
    atomicAdd(&cnt[v], 1);
}

#define SCH 20
__global__ __launch_bounds__(1024) void scan_kernel(const int* __restrict__ cnt,
                                                    int* __restrict__ row_ptr,
                                                    int* __restrict__ cursor,
                                                    int* __restrict__ hist) {
    __shared__ int wtot[16];
    __shared__ int woff[16];
    int t = threadIdx.x;
    if (t < 256) hist[t] = 0;            // zero degree-histogram for the sort
    int lane = t & 63;
    int wid = t >> 6;
    int base = t * SCH;
    int vals[SCH];
    int s = 0;
    #pragma unroll
    for (int i = 0; i < SCH; i++) {
        int idx = base + i;
        int v = (idx < NN) ? cnt[idx] : 0;
        vals[i] = v;
        s += v;
    }
    int incl = s;
    #pragma unroll
    for (int off = 1; off < 64; off <<= 1) {
        int u = __shfl_up(incl, off);
        if (lane >= off) incl += u;
    }
    int excl = incl - s;
    if (lane == 63) wtot[wid] = incl;
    __syncthreads();
    if (t == 0) {
        int run = 0;
        #pragma unroll
        for (int j = 0; j < 16; j++) { woff[j] = run; run += wtot[j]; }
        row_ptr[NN] = run;
    }
    __syncthreads();
    int run = woff[wid] + excl;
    #pragma unroll
    for (int i = 0; i < SCH; i++) {
        int idx = base + i;
        if (idx < NN) { row_ptr[idx] = run; cursor[idx] = run; run += vals[i]; }
    }
}

__global__ void fill_kernel(const int* __restrict__ ei, int* __restrict__ cursor,
                            int* __restrict__ csr_src) {
    int i = blockIdx.x * blockDim.x + threadIdx.x;
    if (i >= ETOT) return;
    int u, v;
    if (i < EE) { u = ei[i]; v = ei[EE + i]; }
    else        { u = i - EE; v = i - EE; }
    int pos = atomicAdd(&cursor[v], 1);
    csr_src[pos] = u;
}

// ---------------- degree sort: LDS-aggregated histogram + 256-bin scan + 2-phase scatter ----------------
// Global atomic contention per bin is <= #blocks (79), vs 20000/35 ~ 600-way naive (R12: 56 us).
__global__ __launch_bounds__(256) void hist_kernel(const int* __restrict__ row_ptr,
                                                   int* __restrict__ hist) {
    __shared__ int lh[256];
    int t = threadIdx.x;
    lh[t] = 0;
    __syncthreads();
    int v = blockIdx.x * 256 + t;
    if (v < NN) {
        int deg = min(row_ptr[v + 1] - row_ptr[v], 255);
        atomicAdd(&lh[deg], 1);
    }
    __syncthreads();
    if (lh[t]) atomicAdd(&hist[t], lh[t]);
}

__global__ __launch_bounds__(256) void binscan_kernel(const int* __restrict__ hist,
                                                      int* __restrict__ binoff) {
    __shared__ int wt[4];
    int t = threadIdx.x;
    int lane = t & 63;
    int w = t >> 6;
    int v = hist[t];
    int incl = v;
    #pragma unroll
    for (int off = 1; off < 64; off <<= 1) {
        int u = __shfl_up(incl, off);
        if (lane >= off) incl += u;
    }
    if (lane == 63) wt[w] = incl;
    __syncthreads();
    int add = 0;
    for (int j = 0; j < w; j++) add += wt[j];
    binoff[t] = incl - v + add;          // exclusive prefix
}

__global__ __launch_bounds__(256) void scatter_kernel(const int* __restrict__ row_ptr,
                                                      int* __restrict__ binoff,
                                                      int* __restrict__ perm) {
    __shared__ int lh[256];
    __shared__ int lbase[256];
    int t = threadIdx.x;
    lh[t] = 0;
    __syncthreads();
    int v = blockIdx.x * 256 + t;
    int deg = 0, lpos = 0;
    if (v < NN) {
        deg = min(row_ptr[v + 1] - row_ptr[v], 255);
        lpos = atomicAdd(&lh[deg], 1);   // local rank within block's bin
    }
    __syncthreads();
    if (lh[t]) lbase[t] = atomicAdd(&binoff[t], lh[t]);   // reserve global range
    __syncthreads();
    if (v < NN) perm[lbase[deg] + lpos] = v;
}

// ---------------- MFMA GEMM 128x128 (layers 1 & 2): double-buffered global_load_lds ----------------
// 2-phase pipeline: prologue-stage buf0; per K-step {stage next -> ds_read+MFMA cur ->
// __syncthreads -> flip}. LDS tiles linear [128][32] f16; 16B slot XOR-swizzled via per-lane
// GLOBAL source address (linear dest + inverse-swz source + swz read); ds_read addrs hoisted.
#define BK 32
#define TILE_E (128 * BK)        // elements per tile buffer
#define TILE_B (TILE_E * 2)      // bytes per tile buffer
__global__ __launch_bounds__(512) void gemm_al(const _Float16* __restrict__ A,
                                               const _Float16* __restrict__ Bt,
                                               _Float16* __restrict__ C16,
                                               const float* __restrict__ a_src,
                                               const float* __restrict__ a_dst,
                                               float* __restrict__ als2,
                                               float* __restrict__ ald2,
                                               int M, int K) {
    __shared__ _Float16 sA[2 * TILE_E];
    __shared__ _Float16 sB[2 * TILE_E];
    __shared__ float psum_s[4][128];
    __shared__ float psum_d[4][128];
    int tid = threadIdx.x;
    int lane = tid & 63;
    int wid = tid >> 6;          // 0..7
    int wv_m = wid >> 2;         // 0..1 : 64-row half
    int wv_n = wid & 3;          // 0..3 : 32-col slice
    int m0 = blockIdx.x * 128, n0 = blockIdx.y * 128;
    int quad = lane >> 4;
    int l15 = lane & 15;

    // staging: wave wid owns phys bytes [wid*1024, wid*1024+1024) of each tile
    int phys = wid * 1024 + lane * 16;
    int logical = phys ^ (((phys >> 7) & 3) << 4);   // same row, swizzled 16B slot
    int lrow = logical >> 6;                          // 0..127
    int lcol = (logical >> 4) & 3;                    // 16B slot in row
    int gmA = m0 + lrow;
    const _Float16* gA = A + (size_t)gmA * K + lcol * 8;
    const _Float16* gB = Bt + (size_t)(n0 + lrow) * K + lcol * 8;
    bool aok = (gmA < M);

    // hoisted swizzled ds_read byte offsets
    int ra[4], rb[2];
    #pragma unroll
    for (int i = 0; i < 4; i++) {
        int lb = (wv_m * 64 + i * 16 + l15) * 64 + quad * 16;
        ra[i] = lb ^ (((lb >> 7) & 3) << 4);
    }
    #pragma unroll
    for (int j = 0; j < 2; j++) {
        int lb = (wv_n * 32 + j * 16 + l15) * 64 + quad * 16;
        rb[j] = lb ^ (((lb >> 7) & 3) << 4);
    }

    floatx4 acc[4][2] = {};

    int nt = K / BK;
    int cur = 0;
    {
        _Float16* lA = sA + wid * 512;
        _Float16* lB = sB + wid * 512;
        if (aok)
            __builtin_amdgcn_global_load_lds(
                (const __attribute__((address_space(1))) void*)gA,
                (__attribute__((address_space(3))) void*)lA, 16, 0, 0);
        __builtin_amdgcn_global_load_lds(
            (const __attribute__((address_space(1))) void*)gB,
            (__attribute__((address_space(3))) void*)lB, 16, 0, 0);
    }
    __syncthreads();
    for (int t = 0; t < nt; ++t) {
        if (t + 1 < nt) {
            int k1 = (t + 1) * BK;
            _Float16* lA = sA + (cur ^ 1) * TILE_E + wid * 512;
            _Float16* lB = sB + (cur ^ 1) * TILE_E + wid * 512;
            if (aok)
                __builtin_amdgcn_global_load_lds(
                    (const __attribute__((address_space(1))) void*)(gA + k1),
                    (__attribute__((address_space(3))) void*)lA, 16, 0, 0);
            __builtin_amdgcn_global_load_lds(
                (const __attribute__((address_space(1))) void*)(gB + k1),
                (__attribute__((address_space(3))) void*)lB, 16, 0, 0);
        }
        const char* bA = (const char*)sA + cur * TILE_B;
        const char* bB = (const char*)sB + cur * TILE_B;
        half8 a[4], b[2];
        #pragma unroll
        for (int i = 0; i < 4; i++)
            a[i] = *(const half8*)(bA + ra[i]);
        #pragma unroll
        for (int j = 0; j < 2; j++)
            b[j] = *(const half8*)(bB + rb[j]);
        #pragma unroll
        for (int i = 0; i < 4; i++)
            #pragma unroll
            for (int j = 0; j < 2; j++)
                acc[i][j] = __builtin_amdgcn_mfma_f32_16x16x32_f16(a[i], b[j], acc[i][j], 0, 0, 0);
        __syncthreads();     // drains this step's stage (vmcnt) + ds_reads (lgkm)
        cur ^= 1;
    }
    #pragma unroll
    for (int i = 0; i < 4; i++) {
        #pragma unroll
        for (int r = 0; r < 4; r++) {
            int gm = m0 + wv_m * 64 + i * 16 + quad * 4 + r;
            if (gm < M) {
                #pragma unroll
                for (int j = 0; j < 2; j++)
                    C16[(size_t)gm * HCV + n0 + wv_n * 32 + j * 16 + l15] = (_Float16)acc[i][j][r];
            }
        }
    }
    // fused half-logit epilogue (prescaled by log2e); als/ald head-major [h][node]
    int h0 = n0 >> 6;
    int hh = h0 + (wv_n >> 1);
    float as_v[2], ad_v[2];
    #pragma unroll
    for (int j = 0; j < 2; j++) {
        int dim = (wv_n * 32 + j * 16 + l15) & 63;
        as_v[j] = a_src[hh * HID + dim] * LOG2E;
        ad_v[j] = a_dst[hh * HID + dim] * LOG2E;
    }
    #pragma unroll
    for (int i = 0; i < 4; i++) {
        #pragma unroll
        for (int r = 0; r < 4; r++) {
            float ps = acc[i][0][r] * as_v[0] + acc[i][1][r] * as_v[1];
            float pd = acc[i][0][r] * ad_v[0] + acc[i][1][r] * ad_v[1];
            #pragma unroll
            for (int off = 1; off <= 8; off <<= 1) {
                ps += __shfl_xor(ps, off);
                pd += __shfl_xor(pd, off);
            }
            if (l15 == 0) {
                int row = wv_m * 64 + i * 16 + quad * 4 + r;   // 0..127
                psum_s[wv_n][row] = ps;
                psum_d[wv_n][row] = pd;
            }
        }
    }
    __syncthreads();
    if (tid < 128) {
        int gm = m0 + tid;
        if (gm < M) {
            als2[(size_t)h0 * NN + gm]       = psum_s[0][tid] + psum_s[1][tid];
            als2[(size_t)(h0 + 1) * NN + gm] = psum_s[2][tid] + psum_s[3][tid];
            ald2[(size_t)h0 * NN + gm]       = psum_d[0][tid] + psum_d[1][tid];
            ald2[(size_t)(h0 + 1) * NN + gm] = psum_d[2][tid] + psum_d[3][tid];
        }
    }
}

// ---------------- MFMA GEMM 128x128 (layer 3): double-buffered, single-head al3 ----------------
__global__ __launch_bounds__(512) void gemm3(const _Float16* __restrict__ A,
                                             const _Float16* __restrict__ Bt,
                                             _Float16* __restrict__ C16,
                                             const float* __restrict__ a_src,
                                             const float* __restrict__ a_dst,
                                             float* __restrict__ als,
                                             float* __restrict__ ald,
                                             int M, int K) {
    __shared__ _Float16 sA[2 * TILE_E];
    __shared__ _Float16 sB[2 * TILE_E];
    __shared__ float psum_s[4][128];
    __shared__ float psum_d[4][128];
    int tid = threadIdx.x;
    int lane = tid & 63;
    int wid = tid >> 6;          // 0..7
    int wv_m = wid >> 2;         // 0..1
    int wv_n = wid & 3;          // 0..3
    int m0 = blockIdx.x * 128;
    int quad = lane >> 4;
    int l15 = lane & 15;

    int phys = wid * 1024 + lane * 16;
    int logical = phys ^ (((phys >> 7) & 3) << 4);
    int lrow = logical >> 6;
    int lcol = (logical >> 4) & 3;
    int gmA = m0 + lrow;
    const _Float16* gA = A + (size_t)gmA * K + lcol * 8;
    const _Float16* gB = Bt + (size_t)lrow * K + lcol * 8;   // n0 = 0, 128 rows = all of OUTD
    bool aok = (gmA < M);

    int ra[4], rb[2];
    #pragma unroll
    for (int i = 0; i < 4; i++) {
        int lb = (wv_m * 64 + i * 16 + l15) * 64 + quad * 16;
        ra[i] = lb ^ (((lb >> 7) & 3) << 4);
    }
    #pragma unroll
    for (int j = 0; j < 2; j++) {
        int lb = (wv_n * 32 + j * 16 + l15) * 64 + quad * 16;
        rb[j] = lb ^ (((lb >> 7) & 3) << 4);
    }

    floatx4 acc[4][2] = {};

    int nt = K / BK;
    int cur = 0;
    {
        _Float16* lA = sA + wid * 512;
        _Float16* lB = sB + wid * 512;
        if (aok)
            __builtin_amdgcn_global_load_lds(
                (const __attribute__((address_space(1))) void*)gA,
                (__attribute__((address_space(3))) void*)lA, 16, 0, 0);
        __builtin_amdgcn_global_load_lds(
            (const __attribute__((address_space(1))) void*)gB,
            (__attribute__((address_space(3))) void*)lB, 16, 0, 0);
    }
    __syncthreads();
    for (int t = 0; t < nt; ++t) {
        if (t + 1 < nt) {
            int k1 = (t + 1) * BK;
            _Float16* lA = sA + (cur ^ 1) * TILE_E + wid * 512;
            _Float16* lB = sB + (cur ^ 1) * TILE_E + wid * 512;
            if (aok)
                __builtin_amdgcn_global_load_lds(
                    (const __attribute__((address_space(1))) void*)(gA + k1),
                    (__attribute__((address_space(3))) void*)lA, 16, 0, 0);
            __builtin_amdgcn_global_load_lds(
                (const __attribute__((address_space(1))) void*)(gB + k1),
                (__attribute__((address_space(3))) void*)lB, 16, 0, 0);
        }
        const char* bA = (const char*)sA + cur * TILE_B;
        const char* bB = (const char*)sB + cur * TILE_B;
        half8 a[4], b[2];
        #pragma unroll
        for (int i = 0; i < 4; i++)
            a[i] = *(const half8*)(bA + ra[i]);
        #pragma unroll
        for (int j = 0; j < 2; j++)
            b[j] = *(const half8*)(bB + rb[j]);
        #pragma unroll
        for (int i = 0; i < 4; i++)
            #pragma unroll
            for (int j = 0; j < 2; j++)
                acc[i][j] = __builtin_amdgcn_mfma_f32_16x16x32_f16(a[i], b[j], acc[i][j], 0, 0, 0);
        __syncthreads();
        cur ^= 1;
    }
    #pragma unroll
    for (int i = 0; i < 4; i++) {
        #pragma unroll
        for (int r = 0; r < 4; r++) {
            int gm = m0 + wv_m * 64 + i * 16 + quad * 4 + r;
            if (gm < M) {
                #pragma unroll
                for (int j = 0; j < 2; j++)
                    C16[(size_t)gm * OUTD + wv_n * 32 + j * 16 + l15] = (_Float16)acc[i][j][r];
            }
        }
    }
    // single-head al3 epilogue (prescaled by log2e): reduce over all 128 cols
    float as_v[2], ad_v[2];
    #pragma unroll
    for (int j = 0; j < 2; j++) {
        int dim = wv_n * 32 + j * 16 + l15;      // 0..127
        as_v[j] = a_src[dim] * LOG2E;
        ad_v[j] = a_dst[dim] * LOG2E;
    }
    #pragma unroll
    for (int i = 0; i < 4; i++) {
        #pragma unroll
        for (int r = 0; r < 4; r++) {
            float ps = acc[i][0][r] * as_v[0] + acc[i][1][r] * as_v[1];
            float pd = acc[i][0][r] * ad_v[0] + acc[i][1][r] * ad_v[1];
            #pragma unroll
            for (int off = 1; off <= 8; off <<= 1) {
                ps += __shfl_xor(ps, off);
                pd += __shfl_xor(pd, off);
            }
            if (l15 == 0) {
                int row = wv_m * 64 + i * 16 + quad * 4 + r;   // 0..127
                psum_s[wv_n][row] = ps;
                psum_d[wv_n][row] = pd;
            }
        }
    }
    __syncthreads();
    if (tid < 128) {
        int gm = m0 + tid;
        if (gm < M) {
            als[gm] = psum_s[0][tid] + psum_s[1][tid] + psum_s[2][tid] + psum_s[3][tid];
            ald[gm] = psum_d[0][tid] + psum_d[1][tid] + psum_d[2][tid] + psum_d[3][tid];
        }
    }
}

// ---------------- gather (layers 1 & 2): degree-sorted, wave = (1 head, 4 nodes x 2 walkers) ----------------
// v = perm[idx]: counting-sorted by degree, so the 4 nodes in a wave have near-equal degree
// (wave time = max of group ranges -> ~mean). head = blockIdx.x & 7 keeps the per-XCD working
// set at one head slice (2.56 MB h + 80 KB als). shfl_xor(8) combines the 2 walkers.
__global__ __launch_bounds__(256) void gather_kernel(const _Float16* __restrict__ h,
                                                     const int* __restrict__ row_ptr,
                                                     const int* __restrict__ csr_src,
                                                     const int* __restrict__ perm,
                                                     const float* __restrict__ als2,
                                                     const float* __restrict__ ald2,
                                                     const float* __restrict__ bias,
                                                     _Float16* __restrict__ gout) {
    int tid = threadIdx.x;
    int lane = tid & 63;
    int wid = tid >> 6;
    int bid = blockIdx.x;
    int hd = bid & 7;                    // head == XCD (round-robin)
    int dl = lane & 7;                   // dim octet within the head
    int es = (lane >> 3) & 1;            // edge-walker slot
    int sub = lane >> 4;                 // node slot 0..3
    int vidx = (bid >> 3) * 16 + wid * 4 + sub;
    if (vidx >= NN) return;
    int v = perm[vidx];
    const float* asl = als2 + (size_t)hd * NN;
    float adst = ald2[(size_t)hd * NN + v];
    int s0 = row_ptr[v], s1 = row_ptr[v + 1];
    int mid = (s0 + s1 + 1) >> 1;
    int jb = es ? mid : s0;
    int je = es ? s1 : mid;
    const _Float16* hh = h + hd * HID + dl * 8;
    float acc[8] = {};
    float l = 0.f;
    int j = jb;
    for (; j + 4 <= je; j += 4) {
        int u[4]; float p[4]; half8 xv[4];
        #pragma unroll
        for (int e = 0; e < 4; e++) u[e] = csr_src[j + e];
        #pragma unroll
        for (int e = 0; e < 4; e++) xv[e] = *(const half8*)&hh[(size_t)u[e] * HCV];
        #pragma unroll
        for (int e = 0; e < 4; e++) {
            float t = asl[u[e]] + adst;
            t = fmaxf(t, NEG_SLOPE * t);             // leaky_relu, slope<1
            p[e] = exp2f(fminf(t, 115.f));
        }
        #pragma unroll
        for (int e = 0; e < 4; e++) {
            l += p[e];
            #pragma unroll
            for (int k = 0; k < 8; k++)
                acc[k] = fmaf(p[e], (float)xv[e][k], acc[k]);
        }
    }
    for (; j < je; j++) {
        int u0 = csr_src[j];
        half8 x0 = *(const half8*)&hh[(size_t)u0 * HCV];
        float t0 = asl[u0] + adst;
        t0 = fmaxf(t0, NEG_SLOPE * t0);
        float p0 = exp2f(fminf(t0, 115.f));
        l += p0;
        #pragma unroll
        for (int k = 0; k < 8; k++)
            acc[k] = fmaf(p0, (float)x0[k], acc[k]);
    }
    // combine the two walkers (lanes differ only in bit 3)
    l += __shfl_xor(l, 8);
    #pragma unroll
    for (int k = 0; k < 8; k++)
        acc[k] += __shfl_xor(acc[k], 8);
    if (es == 0) {
        float inv = 1.f / (l + 1e-16f);
        half8 hv;
        #pragma unroll
        for (int k = 0; k < 8; k++) {
            float o = fmaf(acc[k], inv, bias[hd * HID + dl * 8 + k]);
            o = (o > 0.f) ? o : (__expf(o) - 1.f);   // ELU
            hv[k] = (_Float16)o;
        }
        half8* dst = (half8*)&gout[(size_t)v * HCV + hd * HID + dl * 8];
        __builtin_nontemporal_store(hv, dst);
    }
}

// ---------------- layer-3 gather: degree-sorted, single-pass, wave = (1 dim-half, 4 nodes x 2 walkers) ----------------
__global__ __launch_bounds__(256) void gather3_kernel(const _Float16* __restrict__ h,
                                                      const int* __restrict__ row_ptr,
                                                      const int* __restrict__ csr_src,
                                                      const int* __restrict__ perm,
                                                      const float* __restrict__ als,
                                                      const float* __restrict__ ald,
                                                      const float* __restrict__ bias,
                                                      float* __restrict__ out) {
    int tid = threadIdx.x;
    int lane = tid & 63;
    int wid = tid >> 6;
    int bid = blockIdx.x;
    int dh = bid & 1;                    // dim-half (XCD parity)
    int dl = lane & 7;
    int es = (lane >> 3) & 1;
    int sub = lane >> 4;                 // node slot 0..3
    int vidx = (bid >> 1) * 16 + wid * 4 + sub;
    if (vidx >= NN) return;
    int v = perm[vidx];
    float adst = ald[v];
    int s0 = row_ptr[v], s1 = row_ptr[v + 1];
    int mid = (s0 + s1 + 1) >> 1;
    int jb = es ? mid : s0;
    int je = es ? s1 : mid;
    const _Float16* hh = h + dh * 64 + dl * 8;
    float acc[8] = {};
    float l = 0.f;
    int j = jb;
    for (; j + 4 <= je; j += 4) {
        int u[4]; float p[4]; half8 xv[4];
        #pragma unroll
        for (int e = 0; e < 4; e++) u[e] = csr_src[j + e];
        #pragma unroll
        for (int e = 0; e < 4; e++) xv[e] = *(const half8*)&hh[(size_t)u[e] * OUTD];
        #pragma unroll
        for (int e = 0; e < 4; e++) {
            float t = als[u[e]] + adst;
            t = fmaxf(t, NEG_SLOPE * t);
            p[e] = exp2f(fminf(t, 115.f));
        }
        #pragma unroll
        for (int e = 0; e < 4; e++) {
            l += p[e];
            #pragma unroll
            for (int k = 0; k < 8; k++)
                acc[k] = fmaf(p[e], (float)xv[e][k], acc[k]);
        }
    }
    for (; j < je; j++) {
        int u0 = csr_src[j];
        half8 x0 = *(const half8*)&hh[(size_t)u0 * OUTD];
        float t0 = als[u0] + adst;
        t0 = fmaxf(t0, NEG_SLOPE * t0);
        float p0 = exp2f(fminf(t0, 115.f));
        l += p0;
        #pragma unroll
        for (int k = 0; k < 8; k++)
            acc[k] = fmaf(p0, (float)x0[k], acc[k]);
    }
    l += __shfl_xor(l, 8);
    #pragma unroll
    for (int k = 0; k < 8; k++)
        acc[k] += __shfl_xor(acc[k], 8);
    if (es == 0) {
        float inv = 1.f / (l + 1e-16f);
        float4 o0, o1;
        o0.x = fmaf(acc[0], inv, bias[dh * 64 + dl * 8 + 0]);
        o0.y = fmaf(acc[1], inv, bias[dh * 64 + dl * 8 + 1]);
        o0.z = fmaf(acc[2], inv, bias[dh * 64 + dl * 8 + 2]);
        o0.w = fmaf(acc[3], inv, bias[dh * 64 + dl * 8 + 3]);
        o1.x = fmaf(acc[4], inv, bias[dh * 64 + dl * 8 + 4]);
        o1.y = fmaf(acc[5], inv, bias[dh * 64 + dl * 8 + 5]);
        o1.z = fmaf(acc[6], inv, bias[dh * 64 + dl * 8 + 6]);
        o1.w = fmaf(acc[7], inv, bias[dh * 64 + dl * 8 + 7]);
        size_t base = (size_t)v * OUTD + dh * 64 + dl * 8;
        *(float4*)&out[base] = o0;
        *(float4*)&out[base + 4] = o1;
    }
}

// ---------------- launch ----------------

extern "C" void kernel_launch(void* const* d_in, const int* in_sizes, int n_in,
                              void* d_out, int out_size, void* d_ws, size_t ws_size,
                              hipStream_t stream) {
    const float* x     = (const float*)d_in[0];
    const int*   ei    = (const int*)d_in[1];
    const float* W1    = (const float*)d_in[2];
    const float* as1   = (const float*)d_in[3];
    const float* ad1   = (const float*)d_in[4];
    const float* b1    = (const float*)d_in[5];
    const float* W2    = (const float*)d_in[6];
    const float* as2   = (const float*)d_in[7];
    const float* ad2   = (const float*)d_in[8];
    const float* b2    = (const float*)d_in[9];
    const float* W3    = (const float*)d_in[10];
    const float* as3   = (const float*)d_in[11];
    const float* ad3   = (const float*)d_in[12];
    const float* b3    = (const float*)d_in[13];
    float* out = (float*)d_out;

    size_t off = 0;
    auto carve = [&](size_t bytes) {
        void* p = (char*)d_ws + off;
        off += (bytes + 255) & ~(size_t)255;
        return p;
    };
    int* row_ptr   = (int*)carve((NN + 1) * sizeof(int));
    int* cursor    = (int*)carve(NN * sizeof(int));
    int* csr_src   = (int*)carve(ETOT * sizeof(int));
    int* perm      = (int*)carve(NN * sizeof(int));
    int* hist      = (int*)carve(256 * sizeof(int));
    int* binoff    = (int*)carve(256 * sizeof(int));
    _Float16* xh   = (_Float16*)carve((size_t)NN * IND * sizeof(_Float16));
    _Float16* h1   = (_Float16*)carve((size_t)NN * HCV * sizeof(_Float16));
    _Float16* gact = (_Float16*)carve((size_t)NN * HCV * sizeof(_Float16));
    _Float16* hf16 = (_Float16*)carve((size_t)NN * HCV * sizeof(_Float16));
    _Float16* h3   = (_Float16*)carve((size_t)NN * OUTD * sizeof(_Float16));
    float* als     = (float*)carve((size_t)NN * NHEADS * sizeof(float));
    float* ald     = (float*)carve((size_t)NN * NHEADS * sizeof(float));
    _Float16* W1T  = (_Float16*)carve((size_t)S1 * sizeof(_Float16));
    _Float16* W2T  = (_Float16*)carve((size_t)S2 * sizeof(_Float16));
    _Float16* W3T  = (_Float16*)carve((size_t)S3 * sizeof(_Float16));
    _Float16* gact2 = h1;   // aliases h1 (dead after layer-1 gather)
    (void)ws_size; (void)n_in; (void)in_sizes; (void)out_size;

    dim3 blk(256);

    // ---- prep (tiled transposes + x cvt + cnt zero) ----
    int prep_blocks = NT_TOT + XB + (NN + 255) / 256;
    prep_kernel<<<prep_blocks, blk, 0, stream>>>(W1, W2, W3, x, W1T, W2T, W3T, xh, cursor);

    // ---- CSR build + degree sort (LDS-aggregated, low-contention) ----
    count_kernel<<<(ETOT + 255) / 256, blk, 0, stream>>>(ei, cursor);
    scan_kernel<<<1, 1024, 0, stream>>>(cursor, row_ptr, cursor, hist);
    fill_kernel<<<(ETOT + 255) / 256, blk, 0, stream>>>(ei, cursor, csr_src);
    hist_kernel<<<(NN + 255) / 256, blk, 0, stream>>>(row_ptr, hist);
    binscan_kernel<<<1, 256, 0, stream>>>(hist, binoff);
    scatter_kernel<<<(NN + 255) / 256, blk, 0, stream>>>(row_ptr, binoff, perm);

    int mt128 = (NN + 127) / 128;
    int nb4 = (NN + 15) / 16;   // node-blocks for gathers (4 waves x 4 nodes per block)

    // ---- layer 1: project-first (dense GEMM + fused al), then head-sliced gather ----
    gemm_al<<<dim3(mt128, HCV / 128), dim3(512), 0, stream>>>(xh, W1T, h1, as1, ad1, als, ald, NN, IND);
    gather_kernel<<<dim3(nb4 * 8), blk, 0, stream>>>(h1, row_ptr, csr_src, perm, als, ald, b1, gact);

    // ---- layer 2: identical structure ----
    gemm_al<<<dim3(mt128, HCV / 128), dim3(512), 0, stream>>>(gact, W2T, hf16, as2, ad2, als, ald, NN, HCV);
    gather_kernel<<<dim3(nb4 * 8), blk, 0, stream>>>(hf16, row_ptr, csr_src, perm, als, ald, b2, gact2);

    // ---- layer 3: output-side, fp16 h3, dim-half sliced single-pass gather ----
    gemm3<<<dim3(mt128, 1), dim3(512), 0, stream>>>(gact2, W3T, h3, as3, ad3, als, ald, NN, HCV);
    gather3_kernel<<<dim3(nb4 * 2), blk, 0, stream>>>(h3, row_ptr, csr_src, perm, als, ald, b3, out);
}